// Round 7
// baseline (159.712 us; speedup 1.0000x reference)
//
#include <hip/hip_runtime.h>

#define IMG_H 512
#define IMG_W 512
#define IMG_N (IMG_H * IMG_W)
#define NPLANES 48          // 16 batch * 3 channels
#define TILE 64             // 64x64 output tile per block
#define SSIM_C1 0.0001f
#define SSIM_C2 0.0009f

typedef _Float16 f16x2 __attribute__((ext_vector_type(2)));
typedef _Float16 f16x4 __attribute__((ext_vector_type(4)));
typedef _Float16 f16x8 __attribute__((ext_vector_type(8)));
typedef float    f32x4 __attribute__((ext_vector_type(4)));

__device__ __forceinline__ f16x2 pk2h(float a, float b) {   // 1 op: v_cvt_pkrtz
    return __builtin_bit_cast(f16x2, __builtin_amdgcn_cvt_pkrtz(a, b));
}
__device__ __forceinline__ f16x8 pk8(float4 a, float4 b) {  // 4 ops
    const f16x2 r0 = pk2h(a.x, a.y), r1 = pk2h(a.z, a.w);
    const f16x2 r2 = pk2h(b.x, b.y), r3 = pk2h(b.z, b.w);
    return f16x8{r0.x, r0.y, r1.x, r1.y, r2.x, r2.y, r3.x, r3.y};
}

// Separable 11x11 Gaussian conv via MFMA, f16 datapath — STREAMING version.
// No LDS staging: each h_tile's X fragment (row 16h+n15-8, cols
// 16cw-8+8q..+7 relative to tile base) is loaded directly from global as
// 2x float4 per array, packed to f16x8 via v_cvt_pkrtz, and fed to the
// UNCHANGED MFMA datapath:
//   H-pass: D = X(16x32) * Wh(32x16 band) via v_mfma_f32_16x16x32_f16;
//   H's C-layout == B-fragment layout of the K=16 MFMA, so
//   V = W0*H[rt] + W1*H[rt+1] via two v_mfma_f32_16x16x16f16, in-register.
// Why no LDS: HBM traffic is identical (f32 fetched once either way; the
// ~2x intra-block reuse is L1/L2-resident), and removing the stage->barrier
// ->compute convoy lets loads overlap compute continuously (round-4/6
// counters: only ~45% of achievable HBM BW during staging bursts).
// Col fragments are 8-aligned and IMG_W%8==0, so edge handling is
// whole-fragment: clamp address + zero-select, CHECK-templated so the 36/64
// interior xy-blocks carry zero bounds code.
// __launch_bounds__(256,6): round-4-proven cap (85) — round 6 showed that
// over-constraining (cap->32) forces scratch spills (30 MB HBM writes).
template <bool CHECK>
__device__ __forceinline__ float ssim_body(
    const float* __restrict__ pp, const float* __restrict__ tp,
    const int base_r, const int base_c, const int cw,
    const int n15, const int quad,
    const f16x8 wfrag, const f16x4 w0frag, const f16x4 w1frag)
{
    const f32x4 zero4 = {0.f, 0.f, 0.f, 0.f};
    const int gc = base_c + 16 * cw - 8 + 8 * quad;   // loop-invariant

    // H-pass for one 16-row tile h (0..4): 4 global float4 loads ->
    // P[ch] = C-layout result packed to f16x4 (rows 4q+0..3, col n15).
    auto h_tile = [&](int h, f16x4 (&P)[5]) {
        const int gr = base_r - 8 + 16 * h + n15;
        float4 p0, p1, t0, t1;
        if (CHECK) {
            const bool ok = ((unsigned)gr < (unsigned)IMG_H) &&
                            ((unsigned)gc < (unsigned)IMG_W);
            const int grc = min(max(gr, 0), IMG_H - 1);
            const int gcc = min(max(gc, 0), IMG_W - 8);
            const float* pr = pp + grc * IMG_W + gcc;
            const float* tr = tp + grc * IMG_W + gcc;
            p0 = *(const float4*)(pr);     p1 = *(const float4*)(pr + 4);
            t0 = *(const float4*)(tr);     t1 = *(const float4*)(tr + 4);
            if (!ok) {
                const float4 z = make_float4(0.f, 0.f, 0.f, 0.f);
                p0 = z; p1 = z; t0 = z; t1 = z;
            }
        } else {
            const float* pr = pp + gr * IMG_W + gc;
            const float* tr = tp + gr * IMG_W + gc;
            p0 = *(const float4*)(pr);     p1 = *(const float4*)(pr + 4);
            t0 = *(const float4*)(tr);     t1 = *(const float4*)(tr + 4);
        }
        const f16x8 pu = pk8(p0, p1);
        const f16x8 tu = pk8(t0, t1);
        #pragma unroll
        for (int ch = 0; ch < 5; ++ch) {
            f16x8 au;
            if      (ch == 0) au = pu;
            else if (ch == 1) au = tu;
            else if (ch == 2) au = pu * pu;      // v_pk_mul_f16 x4
            else if (ch == 3) au = tu * tu;
            else              au = pu * tu;
            const f32x4 hd = __builtin_amdgcn_mfma_f32_16x16x32_f16(
                au, wfrag, zero4, 0, 0, 0);
            const f16x2 l  = pk2h(hd[0], hd[1]);
            const f16x2 hh = pk2h(hd[2], hd[3]);
            P[ch] = f16x4{l.x, l.y, hh.x, hh.y};
        }
    };

    f16x4 Pprev[5], Pcur[5];
    h_tile(0, Pprev);

    float acc = 0.f;
    #pragma unroll
    for (int rt = 0; rt < 4; ++rt) {
        h_tile(rt + 1, Pcur);
        f32x4 s[5];
        #pragma unroll
        for (int ch = 0; ch < 5; ++ch) {
            const f32x4 t = __builtin_amdgcn_mfma_f32_16x16x16f16(
                w0frag, Pprev[ch], zero4, 0, 0, 0);
            s[ch] = __builtin_amdgcn_mfma_f32_16x16x16f16(
                w1frag, Pcur[ch], t, 0, 0, 0);
        }
        // SSIM for the 4 pixels this lane owns in row-tile rt
        #pragma unroll
        for (int r = 0; r < 4; ++r) {
            const float mu1 = s[0][r], mu2 = s[1][r];
            const float e11 = s[2][r], e22 = s[3][r], e12 = s[4][r];
            const float mu1_sq = mu1 * mu1, mu2_sq = mu2 * mu2;
            const float mu1_mu2 = mu1 * mu2;
            const float s1  = e11 - mu1_sq;
            const float s2  = e22 - mu2_sq;
            const float s12 = e12 - mu1_mu2;
            const float num = (2.f * mu1_mu2 + SSIM_C1) * (2.f * s12 + SSIM_C2);
            const float den = (mu1_sq + mu2_sq + SSIM_C1) * (s1 + s2 + SSIM_C2);
            acc += num * __builtin_amdgcn_rcpf(den);
        }
        #pragma unroll
        for (int ch = 0; ch < 5; ++ch) Pprev[ch] = Pcur[ch];
    }
    return acc;
}

__global__ __launch_bounds__(256, 6) void ssim_mfma_kernel(
    const float* __restrict__ pred, const float* __restrict__ target,
    const float* __restrict__ window, float* __restrict__ partial)
{
    __shared__ unsigned short gfS[16];       // f16 taps, [11..15] = 0
    __shared__ float wsum[4];

    const int tid  = threadIdx.x;
    const int cw   = tid >> 6;       // wave = col-tile (16 cols)
    const int lane = tid & 63;
    const int n15  = lane & 15;
    const int quad = lane >> 4;

    // f16 tap table: g[i] = row sums of the normalized 2D window (RNE cast)
    if (tid < 16) {
        float gv = 0.f;
        if (tid < 11) {
            float s = 0.f;
            #pragma unroll
            for (int j = 0; j < 11; ++j) s += window[tid * 11 + j];
            gv = s;
        }
        const _Float16 hg = (_Float16)gv;
        gfS[tid] = __builtin_bit_cast(unsigned short, hg);
    }
    __syncthreads();

    // ---- H weight fragment (B-op of 16x16x32): elem j -> g[8q+j - n15 - 3]
    uint4 wu;
    {
        unsigned wd[4];
        #pragma unroll
        for (int d = 0; d < 4; ++d) {
            const int t0 = 8 * quad + 2 * d - n15 - 3;
            const unsigned lo = gfS[((unsigned)t0       <= 10u) ? t0       : 11];
            const unsigned hi = gfS[((unsigned)(t0 + 1) <= 10u) ? (t0 + 1) : 11];
            wd[d] = lo | (hi << 16);
        }
        wu = make_uint4(wd[0], wd[1], wd[2], wd[3]);
    }
    const f16x8 wfrag = __builtin_bit_cast(f16x8, wu);

    // ---- V weight fragments (A-op of 16x16x16, k = 4q+j, m = n15):
    // w0[j] = g[k - m - 3]  (H tile rt),  w1[j] = g[k - m + 13]  (tile rt+1)
    f16x4 w0frag, w1frag;
    {
        unsigned a[2], b[2];
        #pragma unroll
        for (int d = 0; d < 2; ++d) {
            const int k0 = 4 * quad + 2 * d;
            const int a0 = k0 - n15 - 3,  a1 = a0 + 1;
            const int b0 = k0 - n15 + 13, b1 = b0 + 1;
            a[d] = gfS[((unsigned)a0 <= 10u) ? a0 : 11] |
                   ((unsigned)gfS[((unsigned)a1 <= 10u) ? a1 : 11] << 16);
            b[d] = gfS[((unsigned)b0 <= 10u) ? b0 : 11] |
                   ((unsigned)gfS[((unsigned)b1 <= 10u) ? b1 : 11] << 16);
        }
        w0frag = __builtin_bit_cast(f16x4, make_uint2(a[0], a[1]));
        w1frag = __builtin_bit_cast(f16x4, make_uint2(b[0], b[1]));
    }

    const int plane  = blockIdx.z;
    const int base_r = blockIdx.y * TILE;
    const int base_c = blockIdx.x * TILE;
    const float* pp = pred   + (size_t)plane * IMG_N;
    const float* tp = target + (size_t)plane * IMG_N;

    const bool interior = (blockIdx.x > 0) && (blockIdx.x < gridDim.x - 1) &&
                          (blockIdx.y > 0) && (blockIdx.y < gridDim.y - 1);
    float acc;
    if (interior)
        acc = ssim_body<false>(pp, tp, base_r, base_c, cw, n15, quad,
                               wfrag, w0frag, w1frag);
    else
        acc = ssim_body<true >(pp, tp, base_r, base_c, cw, n15, quad,
                               wfrag, w0frag, w1frag);

    // ---- Block reduction ----
    #pragma unroll
    for (int off = 32; off > 0; off >>= 1)
        acc += __shfl_down(acc, off, 64);
    if (lane == 0) wsum[cw] = acc;
    __syncthreads();
    if (tid == 0) {
        const int bid = blockIdx.x + gridDim.x * (blockIdx.y + gridDim.y * blockIdx.z);
        partial[bid] = wsum[0] + wsum[1] + wsum[2] + wsum[3];
    }
}

// Reduce 3072 partials -> scalar (double accumulate)
__global__ __launch_bounds__(256) void ssim_reduce_kernel(
    const float* __restrict__ partial, float* __restrict__ out)
{
    const int tid = threadIdx.x;
    float s = 0.f;
    #pragma unroll
    for (int k = 0; k < 12; ++k) s += partial[tid + 256 * k];
    double acc = (double)s;
    #pragma unroll
    for (int off = 32; off > 0; off >>= 1)
        acc += __shfl_down(acc, off, 64);
    __shared__ double wsumd[4];
    const int lane = tid & 63, wid = tid >> 6;
    if (lane == 0) wsumd[wid] = acc;
    __syncthreads();
    if (tid == 0) {
        const double total = wsumd[0] + wsumd[1] + wsumd[2] + wsumd[3];
        const double N = (double)NPLANES * IMG_H * IMG_W;
        out[0] = (float)(1.0 - total / N);
    }
}

extern "C" void kernel_launch(void* const* d_in, const int* in_sizes, int n_in,
                              void* d_out, int out_size, void* d_ws, size_t ws_size,
                              hipStream_t stream)
{
    const float* pred   = (const float*)d_in[0];
    const float* target = (const float*)d_in[1];
    const float* window = (const float*)d_in[2];
    float* out = (float*)d_out;
    float* partial = (float*)d_ws;   // 3072 floats = 12 KiB

    dim3 grid(IMG_W / TILE, IMG_H / TILE, NPLANES);   // (8, 8, 48) = 3072 blocks
    ssim_mfma_kernel<<<grid, 256, 0, stream>>>(pred, target, window, partial);
    ssim_reduce_kernel<<<1, 256, 0, stream>>>(partial, out);
}

// Round 8
// 151.805 us; speedup vs baseline: 1.0521x; 1.0521x over previous
//
#include <hip/hip_runtime.h>

#define IMG_H 512
#define IMG_W 512
#define IMG_N (IMG_H * IMG_W)
#define NPLANES 48          // 16 batch * 3 channels
#define TILE 64             // 64x64 output tile per block
#define XS 80               // LDS row stride (elements); 160B rows, 16B-aligned
#define SSIM_C1 0.0001f
#define SSIM_C2 0.0009f

typedef _Float16 f16x2 __attribute__((ext_vector_type(2)));
typedef _Float16 f16x4 __attribute__((ext_vector_type(4)));
typedef _Float16 f16x8 __attribute__((ext_vector_type(8)));
typedef float    f32x4 __attribute__((ext_vector_type(4)));

__device__ __forceinline__ unsigned pk2(float a, float b) {   // 1 op: v_cvt_pkrtz
    return __builtin_bit_cast(unsigned,
        __builtin_amdgcn_cvt_pkrtz(a, b));                    // a -> low half
}
__device__ __forceinline__ f16x2 pk2h(float a, float b) {
    return __builtin_bit_cast(f16x2, __builtin_amdgcn_cvt_pkrtz(a, b));
}

// One staging item: global row/col from flat item index fi (80 rows x 20
// float4), clamped-address load (CHECK) with post-load zero select.
template <bool CHECK>
__device__ __forceinline__ void load_item(
    const float* __restrict__ pp, const float* __restrict__ tp,
    const unsigned fi, const int base_r, const int base_c,
    float4& p4, float4& t4, unsigned& off, bool& ok)
{
    const unsigned ri = fi / 20u, q = fi - 20u * ri;
    int gr = base_r - 8 + (int)ri;
    int gc = base_c - 8 + 4 * (int)q;
    ok = true;
    if (CHECK) {
        ok = ((unsigned)gr < (unsigned)IMG_H) && ((unsigned)gc < (unsigned)IMG_W);
        gr = min(max(gr, 0), IMG_H - 1);
        gc = min(max(gc, 0), IMG_W - 4);              // keeps 16B alignment
    }
    const int idx = gr * IMG_W + gc;
    p4  = *(const float4*)(pp + idx);
    t4  = *(const float4*)(tp + idx);
    off = ri * XS + 4u * q;                           // 8B-aligned
}

__device__ __forceinline__ void store_item(
    unsigned short* Xp, unsigned short* Xt, const unsigned off,
    float4 p4, float4 t4, const bool zero)
{
    if (zero) {
        p4 = make_float4(0.f, 0.f, 0.f, 0.f);
        t4 = make_float4(0.f, 0.f, 0.f, 0.f);
    }
    *(uint2*)&Xp[off] = make_uint2(pk2(p4.x, p4.y), pk2(p4.z, p4.w));
    *(uint2*)&Xt[off] = make_uint2(pk2(t4.x, t4.y), pk2(t4.z, t4.w));
}

// Separable 11x11 Gaussian conv via MFMA, f16 datapath (round-4 structure:
// LDS-staged, 4 waves, proven no-spill at VGPR 44).
// H-pass: D = X(16x32) * Wh(32x16 band) via v_mfma_f32_16x16x32_f16; H's
// C-layout == B-fragment layout of the K=16 MFMA, so V = W0*H[rt]+W1*H[rt+1]
// via two v_mfma_f32_16x16x16f16 entirely in-register.
// NEW (two-phase staging, mini-T14): Phase A = LDS rows 0..63 (all data for
// h_tiles 0..3 -> output row-tiles 0..2). Phase B = rows 64..79 (1.25
// float4/thread, 16 held VGPRs), ISSUED right after the A-barrier and
// written after rt 0..2 compute -> B's HBM latency hides under ~2/3 of the
// block's compute. Spill guard: only +16 live VGPRs vs round 4 (peak ~70 <
// 85 cap). Round 6/7 lesson: big in-flight-load live sets across the MFMA
// pipeline trigger low-VGPR-cap + scratch spills (WRITE_SIZE tens of MB).
template <bool CHECK>
__device__ __forceinline__ float ssim_body(
    const float* __restrict__ pp, const float* __restrict__ tp,
    unsigned short* Xp, unsigned short* Xt, const unsigned short* gfS,
    const int tid, const int cw, const int n15, const int quad,
    const int base_r, const int base_c)
{
    // ---- Phase A loads: items 0..1279 (LDS rows 0..63), 5 per thread ----
    float4   pa[5], ta[5];
    unsigned offA[5];
    bool     okA[5];
    #pragma unroll
    for (int i = 0; i < 5; ++i)
        load_item<CHECK>(pp, tp, (unsigned)tid + 256u * i, base_r, base_c,
                         pa[i], ta[i], offA[i], okA[i]);

    __syncthreads();   // barrier 1: gfS tap table visible (A loads drain here)

    // ---- H weight fragment (B-op of 16x16x32): elem j -> g[8q+j - n15 - 3]
    uint4 wu;
    {
        unsigned wd[4];
        #pragma unroll
        for (int d = 0; d < 4; ++d) {
            const int t0 = 8 * quad + 2 * d - n15 - 3;
            const unsigned lo = gfS[((unsigned)t0       <= 10u) ? t0       : 11];
            const unsigned hi = gfS[((unsigned)(t0 + 1) <= 10u) ? (t0 + 1) : 11];
            wd[d] = lo | (hi << 16);
        }
        wu = make_uint4(wd[0], wd[1], wd[2], wd[3]);
    }
    const f16x8 wfrag = __builtin_bit_cast(f16x8, wu);

    // ---- V weight fragments (A-op of 16x16x16, k = 4q+j, m = n15):
    // w0[j] = g[k - m - 3]  (H tile rt),  w1[j] = g[k - m + 13]  (tile rt+1)
    f16x4 w0frag, w1frag;
    {
        unsigned a[2], b[2];
        #pragma unroll
        for (int d = 0; d < 2; ++d) {
            const int k0 = 4 * quad + 2 * d;
            const int a0 = k0 - n15 - 3,  a1 = a0 + 1;
            const int b0 = k0 - n15 + 13, b1 = b0 + 1;
            a[d] = gfS[((unsigned)a0 <= 10u) ? a0 : 11] |
                   ((unsigned)gfS[((unsigned)a1 <= 10u) ? a1 : 11] << 16);
            b[d] = gfS[((unsigned)b0 <= 10u) ? b0 : 11] |
                   ((unsigned)gfS[((unsigned)b1 <= 10u) ? b1 : 11] << 16);
        }
        w0frag = __builtin_bit_cast(f16x4, make_uint2(a[0], a[1]));
        w1frag = __builtin_bit_cast(f16x4, make_uint2(b[0], b[1]));
    }
    const f32x4 zero4 = {0.f, 0.f, 0.f, 0.f};

    // ---- Phase A convert + LDS write ----
    #pragma unroll
    for (int i = 0; i < 5; ++i)
        store_item(Xp, Xt, offA[i], pa[i], ta[i], CHECK && !okA[i]);

    __syncthreads();   // barrier 2: LDS rows 0..63 visible

    // ---- Phase B loads ISSUED now (rows 64..79); consumed after rt 0..2 --
    float4   pb0, tb0, pb1, tb1;
    unsigned offB0, offB1;
    bool     okB0, okB1;
    {
        const unsigned fi0 = 1280u + (unsigned)tid;
        unsigned       fi1 = 1536u + (unsigned)tid;
        if (fi1 >= 1600u) fi1 = 1280u;               // dup item (write-guarded)
        load_item<CHECK>(pp, tp, fi0, base_r, base_c, pb0, tb0, offB0, okB0);
        load_item<CHECK>(pp, tp, fi1, base_r, base_c, pb1, tb1, offB1, okB1);
    }

    // H-pass for one 16-row tile h (0..4): 2 b128 X reads, 5 channels ->
    // P[ch] = C-layout result packed to f16x4 (rows 4q+0..3, col n15).
    auto h_tile = [&](int h, f16x4 (&P)[5]) {
        const int xoff = (16 * h + n15) * XS + 16 * cw + 8 * quad;  // 16B-al
        const f16x8 pu = *(const f16x8*)&Xp[xoff];
        const f16x8 tu = *(const f16x8*)&Xt[xoff];
        #pragma unroll
        for (int ch = 0; ch < 5; ++ch) {
            f16x8 au;
            if      (ch == 0) au = pu;
            else if (ch == 1) au = tu;
            else if (ch == 2) au = pu * pu;      // v_pk_mul_f16 x4
            else if (ch == 3) au = tu * tu;
            else              au = pu * tu;
            const f32x4 hd = __builtin_amdgcn_mfma_f32_16x16x32_f16(
                au, wfrag, zero4, 0, 0, 0);
            const f16x2 l  = pk2h(hd[0], hd[1]);
            const f16x2 hh = pk2h(hd[2], hd[3]);
            P[ch] = f16x4{l.x, l.y, hh.x, hh.y};
        }
    };

    float acc = 0.f;
    // V-pass + SSIM for one output row-tile, given consecutive H tiles.
    auto v_ssim = [&](const f16x4 (&Pp)[5], const f16x4 (&Pc)[5]) {
        f32x4 s[5];
        #pragma unroll
        for (int ch = 0; ch < 5; ++ch) {
            const f32x4 t = __builtin_amdgcn_mfma_f32_16x16x16f16(
                w0frag, Pp[ch], zero4, 0, 0, 0);
            s[ch] = __builtin_amdgcn_mfma_f32_16x16x16f16(
                w1frag, Pc[ch], t, 0, 0, 0);
        }
        #pragma unroll
        for (int r = 0; r < 4; ++r) {
            const float mu1 = s[0][r], mu2 = s[1][r];
            const float e11 = s[2][r], e22 = s[3][r], e12 = s[4][r];
            const float mu1_sq = mu1 * mu1, mu2_sq = mu2 * mu2;
            const float mu1_mu2 = mu1 * mu2;
            const float s1  = e11 - mu1_sq;
            const float s2  = e22 - mu2_sq;
            const float s12 = e12 - mu1_mu2;
            const float num = (2.f * mu1_mu2 + SSIM_C1) * (2.f * s12 + SSIM_C2);
            const float den = (mu1_sq + mu2_sq + SSIM_C1) * (s1 + s2 + SSIM_C2);
            acc += num * __builtin_amdgcn_rcpf(den);
        }
    };

    f16x4 Pprev[5], Pcur[5];
    h_tile(0, Pprev);
    #pragma unroll
    for (int rt = 0; rt < 3; ++rt) {       // row-tiles 0..2: LDS rows <= 63
        h_tile(rt + 1, Pcur);
        v_ssim(Pprev, Pcur);
        #pragma unroll
        for (int ch = 0; ch < 5; ++ch) Pprev[ch] = Pcur[ch];
    }

    // ---- Phase B convert + LDS write (rows 64..79), then tail tile ----
    store_item(Xp, Xt, offB0, pb0, tb0, CHECK && !okB0);
    if (tid < 64)
        store_item(Xp, Xt, offB1, pb1, tb1, CHECK && !okB1);

    __syncthreads();   // barrier 3: LDS rows 64..79 visible

    h_tile(4, Pcur);                        // row-tile 3
    v_ssim(Pprev, Pcur);
    return acc;
}

__global__ __launch_bounds__(256, 6) void ssim_mfma_kernel(
    const float* __restrict__ pred, const float* __restrict__ target,
    const float* __restrict__ window, float* __restrict__ partial)
{
    __shared__ __attribute__((aligned(16))) unsigned short Xp[80 * XS]; // 12800 B
    __shared__ __attribute__((aligned(16))) unsigned short Xt[80 * XS]; // 12800 B
    __shared__ unsigned short gfS[16];       // f16 taps, [11..15] = 0
    __shared__ float wsum[4];

    const int tid  = threadIdx.x;
    const int cw   = tid >> 6;       // wave = col-tile (16 cols)
    const int lane = tid & 63;
    const int n15  = lane & 15;
    const int quad = lane >> 4;

    // f16 tap table: g[i] = row sums of the normalized 2D window (RNE cast)
    if (tid < 16) {
        float gv = 0.f;
        if (tid < 11) {
            float s = 0.f;
            #pragma unroll
            for (int j = 0; j < 11; ++j) s += window[tid * 11 + j];
            gv = s;
        }
        const _Float16 hg = (_Float16)gv;
        gfS[tid] = __builtin_bit_cast(unsigned short, hg);
    }

    const int plane  = blockIdx.z;
    const int base_r = blockIdx.y * TILE;
    const int base_c = blockIdx.x * TILE;
    const float* pp = pred   + (size_t)plane * IMG_N;
    const float* tp = target + (size_t)plane * IMG_N;

    const bool interior = (blockIdx.x > 0) && (blockIdx.x < gridDim.x - 1) &&
                          (blockIdx.y > 0) && (blockIdx.y < gridDim.y - 1);
    float acc;
    if (interior)
        acc = ssim_body<false>(pp, tp, Xp, Xt, gfS, tid, cw, n15, quad,
                               base_r, base_c);
    else
        acc = ssim_body<true >(pp, tp, Xp, Xt, gfS, tid, cw, n15, quad,
                               base_r, base_c);

    // ---- Block reduction ----
    #pragma unroll
    for (int off = 32; off > 0; off >>= 1)
        acc += __shfl_down(acc, off, 64);
    if (lane == 0) wsum[cw] = acc;
    __syncthreads();
    if (tid == 0) {
        const int bid = blockIdx.x + gridDim.x * (blockIdx.y + gridDim.y * blockIdx.z);
        partial[bid] = wsum[0] + wsum[1] + wsum[2] + wsum[3];
    }
}

// Reduce 3072 partials -> scalar (double accumulate)
__global__ __launch_bounds__(256) void ssim_reduce_kernel(
    const float* __restrict__ partial, float* __restrict__ out)
{
    const int tid = threadIdx.x;
    float s = 0.f;
    #pragma unroll
    for (int k = 0; k < 12; ++k) s += partial[tid + 256 * k];
    double acc = (double)s;
    #pragma unroll
    for (int off = 32; off > 0; off >>= 1)
        acc += __shfl_down(acc, off, 64);
    __shared__ double wsumd[4];
    const int lane = tid & 63, wid = tid >> 6;
    if (lane == 0) wsumd[wid] = acc;
    __syncthreads();
    if (tid == 0) {
        const double total = wsumd[0] + wsumd[1] + wsumd[2] + wsumd[3];
        const double N = (double)NPLANES * IMG_H * IMG_W;
        out[0] = (float)(1.0 - total / N);
    }
}

extern "C" void kernel_launch(void* const* d_in, const int* in_sizes, int n_in,
                              void* d_out, int out_size, void* d_ws, size_t ws_size,
                              hipStream_t stream)
{
    const float* pred   = (const float*)d_in[0];
    const float* target = (const float*)d_in[1];
    const float* window = (const float*)d_in[2];
    float* out = (float*)d_out;
    float* partial = (float*)d_ws;   // 3072 floats = 12 KiB

    dim3 grid(IMG_W / TILE, IMG_H / TILE, NPLANES);   // (8, 8, 48) = 3072 blocks
    ssim_mfma_kernel<<<grid, 256, 0, stream>>>(pred, target, window, partial);
    ssim_reduce_kernel<<<1, 256, 0, stream>>>(partial, out);
}

// Round 10
// 126.453 us; speedup vs baseline: 1.2630x; 1.2005x over previous
//
#include <hip/hip_runtime.h>

#define IMG_H 512
#define IMG_W 512
#define IMG_N (IMG_H * IMG_W)
#define NPLANES 48          // 16 batch * 3 channels
#define TILE 64             // 64x64 output tile per block
#define XS 80               // LDS row stride (elements); 160B rows, 16B-aligned
#define SSIM_C1 0.0001f
#define SSIM_C2 0.0009f

typedef _Float16 f16x2 __attribute__((ext_vector_type(2)));
typedef _Float16 f16x4 __attribute__((ext_vector_type(4)));
typedef _Float16 f16x8 __attribute__((ext_vector_type(8)));
typedef float    f32x4 __attribute__((ext_vector_type(4)));

__device__ __forceinline__ unsigned pk2(float a, float b) {   // 1 op: v_cvt_pkrtz
    return __builtin_bit_cast(unsigned,
        __builtin_amdgcn_cvt_pkrtz(a, b));                    // a -> low half
}
__device__ __forceinline__ f16x2 pk2h(float a, float b) {
    return __builtin_bit_cast(f16x2, __builtin_amdgcn_cvt_pkrtz(a, b));
}

// Staging: 80x80 region (halo 8) of pred/target as f16 into LDS.
// All 7 (p,t) float4 pairs are loaded into registers FIRST (one latency
// exposure — needs ~56 VGPRs of load results in flight), then converted
// and written. Loads are unconditional (clamped addresses); OOB lanes are
// zeroed by select AFTER the load. Interior blocks (CHECK=false) carry no
// bounds code. All load results die here — nothing stays live across the
// MFMA compute (rounds 6/7/8 showed that cross-compute load liveness
// triggers allocator spills: VGPR pinned 32-40, WRITE_SIZE 30-65 MB).
template <bool CHECK>
__device__ __forceinline__ void stage_inputs(
    const float* __restrict__ pp, const float* __restrict__ tp,
    unsigned short* Xp, unsigned short* Xt,
    const int tid, const int base_r, const int base_c)
{
    float4   pb[7], tb[7];
    unsigned offv[7];
    bool     okv[7];
    #pragma unroll
    for (int i = 0; i < 7; ++i) {
        unsigned fi = (unsigned)tid + 256u * i;       // 80 rows x 20 float4
        if (i == 6) fi = (fi < 1600u) ? fi : 0u;      // dup-load item 0 (safe)
        const unsigned ri = fi / 20u;
        const unsigned q  = fi - 20u * ri;
        int gr = base_r - 8 + (int)ri;
        int gc = base_c - 8 + 4 * (int)q;
        bool ok = true;
        if (CHECK) {
            ok = ((unsigned)gr < (unsigned)IMG_H) && ((unsigned)gc < (unsigned)IMG_W);
            gr = min(max(gr, 0), IMG_H - 1);
            gc = min(max(gc, 0), IMG_W - 4);          // keeps 16B alignment
        }
        const int idx = gr * IMG_W + gc;
        pb[i]   = *(const float4*)(pp + idx);
        tb[i]   = *(const float4*)(tp + idx);
        okv[i]  = ok;
        offv[i] = ri * XS + 4u * q;                   // 8B-aligned
    }
    #pragma unroll
    for (int i = 0; i < 7; ++i) {
        float4 p4 = pb[i], t4 = tb[i];
        if (CHECK && !okv[i]) {
            p4 = make_float4(0.f, 0.f, 0.f, 0.f);
            t4 = make_float4(0.f, 0.f, 0.f, 0.f);
        }
        if (i < 6 || tid < 64) {
            *(uint2*)&Xp[offv[i]] = make_uint2(pk2(p4.x, p4.y), pk2(p4.z, p4.w));
            *(uint2*)&Xt[offv[i]] = make_uint2(pk2(t4.x, t4.y), pk2(t4.z, t4.w));
        }
    }
}

// Separable 11x11 Gaussian conv via MFMA, f16 datapath.
// H-pass: D = X(16x32) * Wh(32x16 band) with v_mfma_f32_16x16x32_f16.
// KEY: H's C-layout (row = 4*quad+reg, col = n15) is EXACTLY the B-fragment
// layout of the K=16 MFMA (k = 4*quad+j, n = n15) — so V consumes H's packed
// output directly in-register: V = W0*H[tile rt] + W1*H[tile rt+1] via two
// v_mfma_f32_16x16x16f16 (W0[m][k]=g[k-m-3], W1[m][k]=g[k-m+13]).
// No Ht LDS, no ds_bpermute, no lgkm ops anywhere in the channel loop.
// Squares/products via v_pk_mul_f16 (no unpack), packs via v_cvt_pkrtz.
//
// __launch_bounds__(256, 4): ALLOCATOR-KNOB EXPERIMENT. Occupancy is
// LDS-capped at 6 blocks/CU (26112 B alloc) regardless; min-4-waves/EU only
// raises the VGPR budget 85 -> 128 so the 7-item staging batch (56 VGPRs of
// load results) can be fully in flight instead of chunked at the previous
// 44-VGPR allocation. Tripwire: WRITE_SIZE > 1 MB = spill -> revert.
__global__ __launch_bounds__(256, 4) void ssim_mfma_kernel(
    const float* __restrict__ pred, const float* __restrict__ target,
    const float* __restrict__ window, float* __restrict__ partial)
{
    __shared__ __attribute__((aligned(16))) unsigned short Xp[80 * XS]; // 12800 B
    __shared__ __attribute__((aligned(16))) unsigned short Xt[80 * XS]; // 12800 B
    __shared__ unsigned short gfS[16];       // f16 taps, [11..15] = 0
    __shared__ float wsum[4];

    const int tid  = threadIdx.x;
    const int w    = tid >> 6;       // wave = col-tile (16 cols)
    const int lane = tid & 63;
    const int n15  = lane & 15;
    const int quad = lane >> 4;

    // f16 tap table: g[i] = row sums of the normalized 2D window (RNE cast)
    if (tid < 16) {
        float gv = 0.f;
        if (tid < 11) {
            float s = 0.f;
            #pragma unroll
            for (int j = 0; j < 11; ++j) s += window[tid * 11 + j];
            gv = s;
        }
        const _Float16 hg = (_Float16)gv;
        gfS[tid] = __builtin_bit_cast(unsigned short, hg);
    }

    const int plane  = blockIdx.z;
    const int base_r = blockIdx.y * TILE;
    const int base_c = blockIdx.x * TILE;
    const float* pp = pred   + (size_t)plane * IMG_N;
    const float* tp = target + (size_t)plane * IMG_N;

    // ---- Stage p,t as f16: rows/cols [base-8, base+71], zero outside ----
    const bool interior = (blockIdx.x > 0) && (blockIdx.x < gridDim.x - 1) &&
                          (blockIdx.y > 0) && (blockIdx.y < gridDim.y - 1);
    if (interior) stage_inputs<false>(pp, tp, Xp, Xt, tid, base_r, base_c);
    else          stage_inputs<true >(pp, tp, Xp, Xt, tid, base_r, base_c);
    __syncthreads();

    // ---- H weight fragment (B-op of 16x16x32): elem j -> g[8q+j - n15 - 3]
    uint4 wu;
    {
        unsigned wd[4];
        #pragma unroll
        for (int d = 0; d < 4; ++d) {
            const int t0 = 8 * quad + 2 * d - n15 - 3;
            const unsigned lo = gfS[((unsigned)t0       <= 10u) ? t0       : 11];
            const unsigned hi = gfS[((unsigned)(t0 + 1) <= 10u) ? (t0 + 1) : 11];
            wd[d] = lo | (hi << 16);
        }
        wu = make_uint4(wd[0], wd[1], wd[2], wd[3]);
    }
    const f16x8 wfrag = __builtin_bit_cast(f16x8, wu);

    // ---- V weight fragments (A-op of 16x16x16, k = 4q+j, m = n15):
    // w0[j] = g[k - m - 3]  (H tile rt),  w1[j] = g[k - m + 13]  (tile rt+1)
    f16x4 w0frag, w1frag;
    {
        unsigned a[2], b[2];
        #pragma unroll
        for (int d = 0; d < 2; ++d) {
            const int k0 = 4 * quad + 2 * d;
            const int a0 = k0 - n15 - 3,  a1 = a0 + 1;
            const int b0 = k0 - n15 + 13, b1 = b0 + 1;
            a[d] = gfS[((unsigned)a0 <= 10u) ? a0 : 11] |
                   ((unsigned)gfS[((unsigned)a1 <= 10u) ? a1 : 11] << 16);
            b[d] = gfS[((unsigned)b0 <= 10u) ? b0 : 11] |
                   ((unsigned)gfS[((unsigned)b1 <= 10u) ? b1 : 11] << 16);
        }
        w0frag = __builtin_bit_cast(f16x4, make_uint2(a[0], a[1]));
        w1frag = __builtin_bit_cast(f16x4, make_uint2(b[0], b[1]));
    }
    const f32x4 zero4 = {0.f, 0.f, 0.f, 0.f};

    // H-pass for one 16-row tile h: 2 b128 X reads, 5 channels ->
    // P[ch] = C-layout result packed to f16x4 (rows 4q+0..3, col n15).
    auto h_tile = [&](int h, f16x4 (&P)[5]) {
        const int xoff = (16 * h + n15) * XS + 16 * w + 8 * quad;  // 16B-al
        const f16x8 pu = *(const f16x8*)&Xp[xoff];
        const f16x8 tu = *(const f16x8*)&Xt[xoff];
        #pragma unroll
        for (int ch = 0; ch < 5; ++ch) {
            f16x8 au;
            if      (ch == 0) au = pu;
            else if (ch == 1) au = tu;
            else if (ch == 2) au = pu * pu;      // v_pk_mul_f16 x4
            else if (ch == 3) au = tu * tu;
            else              au = pu * tu;
            const f32x4 hd = __builtin_amdgcn_mfma_f32_16x16x32_f16(
                au, wfrag, zero4, 0, 0, 0);
            const f16x2 l  = pk2h(hd[0], hd[1]);
            const f16x2 hh = pk2h(hd[2], hd[3]);
            P[ch] = f16x4{l.x, l.y, hh.x, hh.y};
        }
    };

    f16x4 Pprev[5], Pcur[5];
    h_tile(0, Pprev);

    float acc = 0.f;
    #pragma unroll
    for (int rt = 0; rt < 4; ++rt) {
        h_tile(rt + 1, Pcur);
        f32x4 s[5];
        #pragma unroll
        for (int ch = 0; ch < 5; ++ch) {
            const f32x4 t = __builtin_amdgcn_mfma_f32_16x16x16f16(
                w0frag, Pprev[ch], zero4, 0, 0, 0);
            s[ch] = __builtin_amdgcn_mfma_f32_16x16x16f16(
                w1frag, Pcur[ch], t, 0, 0, 0);
        }
        // SSIM for the 4 pixels this lane owns in tile rt
        #pragma unroll
        for (int r = 0; r < 4; ++r) {
            const float mu1 = s[0][r], mu2 = s[1][r];
            const float e11 = s[2][r], e22 = s[3][r], e12 = s[4][r];
            const float mu1_sq = mu1 * mu1, mu2_sq = mu2 * mu2;
            const float mu1_mu2 = mu1 * mu2;
            const float s1  = e11 - mu1_sq;
            const float s2  = e22 - mu2_sq;
            const float s12 = e12 - mu1_mu2;
            const float num = (2.f * mu1_mu2 + SSIM_C1) * (2.f * s12 + SSIM_C2);
            const float den = (mu1_sq + mu2_sq + SSIM_C1) * (s1 + s2 + SSIM_C2);
            acc += num * __builtin_amdgcn_rcpf(den);
        }
        #pragma unroll
        for (int ch = 0; ch < 5; ++ch) Pprev[ch] = Pcur[ch];
    }

    // ---- Block reduction ----
    #pragma unroll
    for (int off = 32; off > 0; off >>= 1)
        acc += __shfl_down(acc, off, 64);
    if (lane == 0) wsum[w] = acc;
    __syncthreads();
    if (tid == 0) {
        const int bid = blockIdx.x + gridDim.x * (blockIdx.y + gridDim.y * blockIdx.z);
        partial[bid] = wsum[0] + wsum[1] + wsum[2] + wsum[3];
    }
}

// Reduce 3072 partials -> scalar (double accumulate)
__global__ __launch_bounds__(256) void ssim_reduce_kernel(
    const float* __restrict__ partial, float* __restrict__ out)
{
    const int tid = threadIdx.x;
    float s = 0.f;
    #pragma unroll
    for (int k = 0; k < 12; ++k) s += partial[tid + 256 * k];
    double acc = (double)s;
    #pragma unroll
    for (int off = 32; off > 0; off >>= 1)
        acc += __shfl_down(acc, off, 64);
    __shared__ double wsumd[4];
    const int lane = tid & 63, wid = tid >> 6;
    if (lane == 0) wsumd[wid] = acc;
    __syncthreads();
    if (tid == 0) {
        const double total = wsumd[0] + wsumd[1] + wsumd[2] + wsumd[3];
        const double N = (double)NPLANES * IMG_H * IMG_W;
        out[0] = (float)(1.0 - total / N);
    }
}

extern "C" void kernel_launch(void* const* d_in, const int* in_sizes, int n_in,
                              void* d_out, int out_size, void* d_ws, size_t ws_size,
                              hipStream_t stream)
{
    const float* pred   = (const float*)d_in[0];
    const float* target = (const float*)d_in[1];
    const float* window = (const float*)d_in[2];
    float* out = (float*)d_out;
    float* partial = (float*)d_ws;   // 3072 floats = 12 KiB

    dim3 grid(IMG_W / TILE, IMG_H / TILE, NPLANES);   // (8, 8, 48) = 3072 blocks
    ssim_mfma_kernel<<<grid, 256, 0, stream>>>(pred, target, window, partial);
    ssim_reduce_kernel<<<1, 256, 0, stream>>>(partial, out);
}